// Round 3
// baseline (233.763 us; speedup 1.0000x reference)
//
#include <hip/hip_runtime.h>
#include <hip/hip_bf16.h>

#define B_ 2
#define C_ 512
#define H_ 50
#define W_ 75
#define N_ 2000
#define SS (1.0f/16.0f)

#define SB (H_ * W_ * C_)   // batch stride (elements), NHWC
#define SH (W_ * C_)        // row stride
#define SW (C_)             // col stride

// lgkm-only barrier: protects LDS ordering WITHOUT draining global
// loads/stores (HIP __syncthreads emits vmcnt(0) -> per-chunk store-drain
// stall, the v4 serializer). "memory" clobber orders all compiler memory ops.
#define BAR_LGKM() asm volatile("s_waitcnt lgkmcnt(0)\n\ts_barrier" ::: "memory")

__device__ __forceinline__ float bf2f(unsigned short u) {
    union { unsigned i; float f; } c; c.i = (unsigned)u << 16; return c.f;
}

// fused transpose+convert: (B,C,H,W) fp32 -> (B,H,W,C) bf16
__global__ __launch_bounds__(256) void transcvt_k(const float* __restrict__ in,
                                                  __hip_bfloat16* __restrict__ out) {
    __shared__ float tile[32][33];
    const int b   = blockIdx.z;
    const int hw0 = blockIdx.x * 32;
    const int c0  = blockIdx.y * 32;
    const int tx  = threadIdx.x;
    const int ty  = threadIdx.y;
    #pragma unroll
    for (int r = 0; r < 32; r += 8) {
        int c  = c0 + ty + r;
        int hw = hw0 + tx;
        if (c < C_ && hw < H_ * W_)
            tile[ty + r][tx] = in[(b * C_ + c) * (H_ * W_) + hw];
    }
    __syncthreads();
    #pragma unroll
    for (int r = 0; r < 32; r += 8) {
        int hw = hw0 + ty + r;
        int c  = c0 + tx;
        if (hw < H_ * W_ && c < C_)
            out[(b * (H_ * W_) + hw) * C_ + c] = __float2bfloat16(tile[tx][ty + r]);
    }
}

// v5: software-pipelined chunk loop.
//  - sval double-buffered: ONE lgkm-only barrier per chunk (was 2 full-drain).
//  - loads for chunk t+1 issued before the barrier; stay in flight across
//    barrier + reduce(t); consumed by write(t+1) with counted vmcnt (stores
//    of reduce never drained -> background HBM write drain).
//  - channel-major sval stride 65: write 2-way banks (free), read stride-1.
//  - reduce index math incremental (no per-output /49, /7).
__global__ __launch_bounds__(256, 4) void roi_avg_v5(
    const __hip_bfloat16* __restrict__ ftb, const float* __restrict__ rois,
    float* __restrict__ out)
{
    __shared__ float  sval[2][64 * 65];   // [buf][chan-in-chunk*65 + sample]
    __shared__ float4 swt[64];
    __shared__ int    soff[64];

    const int n   = blockIdx.x;
    const int tid = threadIdx.x;

    if (tid < 64) {
        const int s = tid;
        const int j = s >> 3;
        const int i = s & 7;
        const float bfv = rois[n * 5 + 0];
        const float x1 = rois[n * 5 + 1] * SS;
        const float y1 = rois[n * 5 + 2] * SS;
        const float x2 = rois[n * 5 + 3] * SS;
        const float y2 = rois[n * 5 + 4] * SS;
        const int b = (int)bfv;
        const float roi_w = fmaxf(x2 - x1 + 1.0f, 0.0f);
        const float roi_h = fmaxf(y2 - y1 + 1.0f, 0.0f);
        const float h = y1 + (float)j * (roi_h / 7.0f);
        const float w = x1 + (float)i * (roi_w / 7.0f);
        const bool valid = (h >= 0.0f) && (h < (float)H_) &&
                           (w >= 0.0f) && (w < (float)W_);
        int hs = (int)floorf(h); hs = hs < 0 ? 0 : (hs > H_ - 2 ? H_ - 2 : hs);
        int ws = (int)floorf(w); ws = ws < 0 ? 0 : (ws > W_ - 2 ? W_ - 2 : ws);
        const float hr = h - (float)hs;
        const float wr = w - (float)ws;
        const float vz = valid ? 1.0f : 0.0f;
        float4 wt;
        wt.x = (1.0f - hr) * (1.0f - wr) * vz;
        wt.y = (1.0f - hr) * wr * vz;
        wt.z = hr * (1.0f - wr) * vz;
        wt.w = hr * wr * vz;
        swt[s]  = wt;
        soff[s] = b * SB + hs * SH + ws * SW;
    }
    __syncthreads();

    const unsigned short* const ft = (const unsigned short*)ftb;
    const int lane = tid & 63;
    const int wv   = tid >> 6;
    const int q    = lane >> 4;        // sample sub-index 0..3
    const int l    = lane & 15;        // channel-quad index
    const int cl   = l * 4;            // channel within chunk (0..63)

    int offk[4];
    #pragma unroll
    for (int k = 0; k < 4; ++k) offk[k] = soff[wv * 16 + k * 4 + q];

    // incremental output indexing: o = r*256 + tid = c*49 + ji
    const int c_init  = tid / 49;
    const int ji_init = tid - c_init * 49;
    const int out_roi = n * (C_ * 49);

    ushort4 a[4], b4[4], cc[4], dd[4];   // one in-flight gather set (32 VGPR)

    auto loadc = [&](int chunk) {
        #pragma unroll
        for (int k = 0; k < 4; ++k) {
            const unsigned short* p = ft + (offk[k] + chunk * 64 + cl);
            a[k]  = *(const ushort4*)(p);
            b4[k] = *(const ushort4*)(p + SW);
            cc[k] = *(const ushort4*)(p + SH);
            dd[k] = *(const ushort4*)(p + SH + SW);
        }
    };

    auto writec = [&](float* dst) {
        #pragma unroll
        for (int k = 0; k < 4; ++k) {
            const int s = wv * 16 + k * 4 + q;
            const float4 wt = swt[s];
            const float v0 = bf2f(a[k].x) * wt.x + bf2f(b4[k].x) * wt.y + bf2f(cc[k].x) * wt.z + bf2f(dd[k].x) * wt.w;
            const float v1 = bf2f(a[k].y) * wt.x + bf2f(b4[k].y) * wt.y + bf2f(cc[k].y) * wt.z + bf2f(dd[k].y) * wt.w;
            const float v2 = bf2f(a[k].z) * wt.x + bf2f(b4[k].z) * wt.y + bf2f(cc[k].z) * wt.z + bf2f(dd[k].z) * wt.w;
            const float v3 = bf2f(a[k].w) * wt.x + bf2f(b4[k].w) * wt.y + bf2f(cc[k].w) * wt.z + bf2f(dd[k].w) * wt.w;
            dst[(cl + 0) * 65 + s] = v0;
            dst[(cl + 1) * 65 + s] = v1;
            dst[(cl + 2) * 65 + s] = v2;
            dst[(cl + 3) * 65 + s] = v3;
        }
    };

    auto reduce = [&](int t, const float* sv_base) {
        const int out_base = out_roi + t * (64 * 49);
        int c = c_init, ji = ji_init;
        #pragma unroll
        for (int r = 0; r < 13; ++r) {
            if (r < 12 || tid < 64) {
                const int jj = (ji * 147) >> 10;           // ji/7, valid ji<=48
                const int s  = ji + jj;                    // j*8+i
                const float* sv = sv_base + c * 65 + s;
                out[out_base + r * 256 + tid] =
                    0.25f * (sv[0] + sv[1] + sv[8] + sv[9]);
            }
            ji += 11; c += 5;                              // o += 256 = 5*49+11
            if (ji >= 49) { ji -= 49; ++c; }
        }
    };

    // pipeline: load0, write0, load1, BAR | {reduce(t-1), write(t), load(t+1), BAR} | ...
    loadc(0);
    writec(sval[0]);
    loadc(1);
    BAR_LGKM();
    #pragma unroll 1
    for (int m = 0; m < 3; ++m) {
        const int t = 2 * m;                 // even chunk
        reduce(t, sval[0]);
        writec(sval[1]);                     // chunk t+1 (odd)
        loadc(t + 2);
        BAR_LGKM();
        reduce(t + 1, sval[1]);
        writec(sval[0]);                     // chunk t+2 (even)
        loadc(t + 3);                        // m=2 -> loadc(7)
        BAR_LGKM();
    }
    reduce(6, sval[0]);
    writec(sval[1]);                         // chunk 7
    BAR_LGKM();
    reduce(7, sval[1]);
}

// Fallback: fp32 native-layout version (only if ws too small)
__global__ __launch_bounds__(256) void roi_avg_generic(
    const float* __restrict__ ft, const float* __restrict__ rois,
    float* __restrict__ out, int sB, int sH, int sW, int sC)
{
    __shared__ float  sval[64 * 65];
    __shared__ float4 swt[64];
    __shared__ int    soff[64];
    const int n   = blockIdx.x;
    const int tid = threadIdx.x;
    if (tid < 64) {
        const int s = tid;
        const int j = s >> 3;
        const int i = s & 7;
        const float bfv = rois[n * 5 + 0];
        const float x1 = rois[n * 5 + 1] * SS;
        const float y1 = rois[n * 5 + 2] * SS;
        const float x2 = rois[n * 5 + 3] * SS;
        const float y2 = rois[n * 5 + 4] * SS;
        const int b = (int)bfv;
        const float roi_w = fmaxf(x2 - x1 + 1.0f, 0.0f);
        const float roi_h = fmaxf(y2 - y1 + 1.0f, 0.0f);
        const float h = y1 + (float)j * (roi_h / 7.0f);
        const float w = x1 + (float)i * (roi_w / 7.0f);
        const bool valid = (h >= 0.0f) && (h < (float)H_) && (w >= 0.0f) && (w < (float)W_);
        int hs = (int)floorf(h); hs = hs < 0 ? 0 : (hs > H_ - 2 ? H_ - 2 : hs);
        int ws = (int)floorf(w); ws = ws < 0 ? 0 : (ws > W_ - 2 ? W_ - 2 : ws);
        const float hr = h - (float)hs;
        const float wr = w - (float)ws;
        const float vz = valid ? 1.0f : 0.0f;
        float4 wt;
        wt.x = (1.0f - hr) * (1.0f - wr) * vz;
        wt.y = (1.0f - hr) * wr * vz;
        wt.z = hr * (1.0f - wr) * vz;
        wt.w = hr * wr * vz;
        swt[s]  = wt;
        soff[s] = b * sB + hs * sH + ws * sW;
    }
    __syncthreads();
    const int lane = tid & 63;
    const int wv   = tid >> 6;
    for (int chunk = 0; chunk < C_ / 64; ++chunk) {
        const int cbase = (chunk * 64 + lane) * sC;
        #pragma unroll 4
        for (int k = 0; k < 16; ++k) {
            const int s = wv * 16 + k;
            const float4 wt = swt[s];
            const int off = soff[s] + cbase;
            sval[lane * 65 + s] = ft[off]            * wt.x + ft[off + sW]      * wt.y +
                                  ft[off + sH]       * wt.z + ft[off + sH + sW] * wt.w;
        }
        __syncthreads();
        const int out_base = n * (C_ * 49) + chunk * (64 * 49);
        #pragma unroll
        for (int r = 0; r < 13; ++r) {
            const int o = r * 256 + tid;
            if (o < 64 * 49) {
                const int c  = o / 49;
                const int ji = o - c * 49;
                const int jj = ji / 7;
                const int s  = ji + jj;
                const float* sv = &sval[c * 65 + s];
                out[out_base + o] = 0.25f * (sv[0] + sv[1] + sv[8] + sv[9]);
            }
        }
        __syncthreads();
    }
}

extern "C" void kernel_launch(void* const* d_in, const int* in_sizes, int n_in,
                              void* d_out, int out_size, void* d_ws, size_t ws_size,
                              hipStream_t stream) {
    const float* features = (const float*)d_in[0];
    const float* rois     = (const float*)d_in[1];
    float* out            = (float*)d_out;

    const size_t need = (size_t)B_ * C_ * H_ * W_ * sizeof(__hip_bfloat16);
    if (ws_size >= need) {
        __hip_bfloat16* ftb = (__hip_bfloat16*)d_ws;
        dim3 g((H_ * W_ + 31) / 32, (C_ + 31) / 32, B_);
        dim3 b(32, 8, 1);
        transcvt_k<<<g, b, 0, stream>>>(features, ftb);
        roi_avg_v5<<<N_, 256, 0, stream>>>(ftb, rois, out);
    } else {
        roi_avg_generic<<<N_, 256, 0, stream>>>(features, rois, out,
                                                C_ * H_ * W_, W_, 1, H_ * W_);
    }
}